// Round 10
// baseline (157.771 us; speedup 1.0000x reference)
//
#include <hip/hip_runtime.h>
#include <hip/hip_bf16.h>
#include <cmath>

// AddictiveAttention: B=32, C=512, HW=1024, HID=256, MEM=256
// out = [a3: 32*1024 | context: 32*512] f32
//
// K1 prep: h3 = h@Wlin.T + blin ; W_conv1 -> Whi/Wlo bf16 split
// K2 fused_mfma (v3): 32x32x16 MFMA, A=W from global (L2), B=x via
//    global_load_lds f32 + on-the-fly hi/lo frag build (shared across waves),
//    3-term split product, tanh + Wattn k-reduce -> direct a2 store
// K3 softmax_context: softmax(a2[b]) -> a3, context

typedef __bf16 bf16;
typedef __attribute__((ext_vector_type(8))) __bf16 bf16x8;
typedef __attribute__((ext_vector_type(16))) float f32x16;

// ---------------- K1: prep (h3 + W split) ----------------
__global__ __launch_bounds__(256) void prep_kernel(const float* __restrict__ h,
                                                   const float* __restrict__ Wlin,
                                                   const float* __restrict__ blin,
                                                   const float* __restrict__ Wc,
                                                   float* __restrict__ h3,
                                                   bf16* __restrict__ Whi,
                                                   bf16* __restrict__ Wlo) {
    const int tid = threadIdx.x;
    if (blockIdx.x < 32) {
        const int b = blockIdx.x;
        __shared__ float hs[256];
        hs[tid] = h[b * 256 + tid];
        __syncthreads();
        const float4* wr = (const float4*)(Wlin + (size_t)tid * 256);
        float acc = blin[tid];
        #pragma unroll 8
        for (int q = 0; q < 64; ++q) {
            float4 w = wr[q];
            float4 hv = *(const float4*)&hs[q * 4];
            acc = fmaf(w.x, hv.x, fmaf(w.y, hv.y, fmaf(w.z, hv.z, fmaf(w.w, hv.w, acc))));
        }
        h3[b * 256 + tid] = acc;
    } else {
        const int e0 = (blockIdx.x - 32) * 2048 + tid * 8;
        float4 v0 = *(const float4*)(Wc + e0);
        float4 v1 = *(const float4*)(Wc + e0 + 4);
        float vs[8] = {v0.x, v0.y, v0.z, v0.w, v1.x, v1.y, v1.z, v1.w};
        bf16x8 vh, vl;
        #pragma unroll
        for (int j = 0; j < 8; ++j) {
            bf16 hi = (bf16)vs[j];
            float r = vs[j] - (float)hi;
            vh[j] = hi;
            vl[j] = (bf16)r;
        }
        *(bf16x8*)&Whi[e0] = vh;
        *(bf16x8*)&Wlo[e0] = vl;
    }
}

// ---------------- K2: v3 fused MFMA ----------------
// Block: batch b x 64 s-cols, ALL 256 k. 4 waves; wave w: k in [64w, 64w+64).
// Wave-tile 64k x 64s via 2mf x 2nf of 32x32x16.
// A (W hi/lo) global->regs. B (x) f32 -> LDS (global_load_lds, dbuf) ->
// per-wave frag build (wave w builds kk=w) -> lane-indexed frag LDS.
__global__ __launch_bounds__(256, 2) void fused_mfma(const float* __restrict__ x,
                                                     const bf16* __restrict__ Whi,
                                                     const bf16* __restrict__ Wlo,
                                                     const float* __restrict__ h3,
                                                     const float* __restrict__ Wattn,
                                                     float* __restrict__ a2) {
    __shared__ float xbuf[2][64 * 64];   // 32 KB: x tile f32 [c][s], double-buffered
    __shared__ bf16x8 fragB[16 * 64];    // 16 KB: [kk*4 + nf*2 + hl][lane]
    __shared__ float red2[4 * 64];       // 1 KB

    const int tid = threadIdx.x;
    const int bid = blockIdx.x;
    // XCD-chunked swizzle (512 % 8 == 0 -> bijective): 4 whole batches per XCD
    const int wk = (bid & 7) * 64 + (bid >> 3);
    const int b  = wk >> 4;
    const int s0 = (wk & 15) * 64;

    const int w  = tid >> 6;   // wave 0..3 -> k in [64w, 64w+64)
    const int l  = tid & 63;
    const int h  = l >> 5;     // k-group half
    const int lr = l & 31;     // row/col within 32

    const float* xb = x + ((size_t)b << 19) + s0;

    // A base pointers (lane-fixed row, 8h element base)
    const bf16* aphi[2];
    const bf16* aplo[2];
    #pragma unroll
    for (int mf = 0; mf < 2; ++mf) {
        const size_t kr = (size_t)(64 * w + 32 * mf + lr) * 512 + 8 * h;
        aphi[mf] = Whi + kr;
        aplo[mf] = Wlo + kr;
    }

    f32x16 acc[2][2];
    #pragma unroll
    for (int mf = 0; mf < 2; ++mf)
        #pragma unroll
        for (int nf = 0; nf < 2; ++nf)
            #pragma unroll
            for (int r = 0; r < 16; ++r) acc[mf][nf][r] = 0.f;

    // ---- stage tile tt into xbuf[nb] via global_load_lds (4 x 16B / thread) ----
    auto stage = [&](int tt, int nb) {
        #pragma unroll
        for (int q = 0; q < 4; ++q) {
            const float* g = xb + (size_t)(tt * 64 + 16 * q + 4 * w + (l >> 4)) * 1024
                                + 4 * (l & 15);
            __builtin_amdgcn_global_load_lds(
                (const __attribute__((address_space(1))) void*)g,
                (__attribute__((address_space(3))) void*)((char*)&xbuf[nb][0] + q * 4096 + w * 1024),
                16, 0, 0);
        }
    };

    stage(0, 0);

    #pragma unroll 1
    for (int t = 0; t < 8; ++t) {
        const int cur = t & 1;
        const int c0 = t * 64;
        __syncthreads();  // bar A: drains stage(t) gloads; guards fragB reuse

        // ---- A-frag loads (global, L2-hot): 16 x bf16x8 ----
        bf16x8 ah[2][4], al[2][4];
        #pragma unroll
        for (int mf = 0; mf < 2; ++mf)
            #pragma unroll
            for (int kk = 0; kk < 4; ++kk) {
                ah[mf][kk] = *(const bf16x8*)(aphi[mf] + c0 + 16 * kk);
                al[mf][kk] = *(const bf16x8*)(aplo[mf] + c0 + 16 * kk);
            }

        // ---- B-frag build: wave w builds kk=w for nf=0,1 (hi+lo) ----
        #pragma unroll
        for (int nf = 0; nf < 2; ++nf) {
            const int base = (16 * w + 8 * h) * 64 + 32 * nf + lr;  // dword idx in xbuf
            float f[8];
            #pragma unroll
            for (int j = 0; j < 8; ++j) f[j] = xbuf[cur][base + j * 64];
            bf16x8 vh, vl;
            #pragma unroll
            for (int j = 0; j < 8; ++j) {
                bf16 hh = (bf16)f[j];
                vh[j] = hh;
                vl[j] = (bf16)(f[j] - (float)hh);
            }
            fragB[(w * 4 + nf * 2 + 0) * 64 + l] = vh;
            fragB[(w * 4 + nf * 2 + 1) * 64 + l] = vl;
        }
        __syncthreads();  // bar B: frags ready

        if (t < 7) stage(t + 1, cur ^ 1);  // async fill next buffer under MFMA

        // ---- MFMA: 4 kk x 2 mf x 2 nf x 3 terms ----
        #pragma unroll
        for (int kk = 0; kk < 4; ++kk) {
            bf16x8 bh0 = fragB[(kk * 4 + 0) * 64 + l];
            bf16x8 bl0 = fragB[(kk * 4 + 1) * 64 + l];
            bf16x8 bh1 = fragB[(kk * 4 + 2) * 64 + l];
            bf16x8 bl1 = fragB[(kk * 4 + 3) * 64 + l];
            #pragma unroll
            for (int mf = 0; mf < 2; ++mf) {
                acc[mf][0] = __builtin_amdgcn_mfma_f32_32x32x16_bf16(ah[mf][kk], bh0, acc[mf][0], 0, 0, 0);
                acc[mf][0] = __builtin_amdgcn_mfma_f32_32x32x16_bf16(ah[mf][kk], bl0, acc[mf][0], 0, 0, 0);
                acc[mf][0] = __builtin_amdgcn_mfma_f32_32x32x16_bf16(al[mf][kk], bh0, acc[mf][0], 0, 0, 0);
                acc[mf][1] = __builtin_amdgcn_mfma_f32_32x32x16_bf16(ah[mf][kk], bh1, acc[mf][1], 0, 0, 0);
                acc[mf][1] = __builtin_amdgcn_mfma_f32_32x32x16_bf16(ah[mf][kk], bl1, acc[mf][1], 0, 0, 0);
                acc[mf][1] = __builtin_amdgcn_mfma_f32_32x32x16_bf16(al[mf][kk], bh1, acc[mf][1], 0, 0, 0);
            }
        }
    }

    // ---- epilogue: tanh + Wattn k-reduce ----
    // C/D: col = lr (s rel 32nf), row = (reg&3) + 8*(reg>>2) + 4*h (+32mf +64w)
    const float* h3b = h3 + b * 256;
    float part[2] = {0.f, 0.f};
    #pragma unroll
    for (int mf = 0; mf < 2; ++mf) {
        #pragma unroll
        for (int r = 0; r < 16; ++r) {
            const int k = 64 * w + 32 * mf + (r & 3) + 8 * (r >> 2) + 4 * h;
            const float hv = h3b[k];
            const float wt = Wattn[k];
            part[0] += wt * tanhf(acc[mf][0][r] + hv);
            part[1] += wt * tanhf(acc[mf][1][r] + hv);
        }
    }
    // combine h halves (same s-col in lanes l and l^32)
    part[0] += __shfl_xor(part[0], 32, 64);
    part[1] += __shfl_xor(part[1], 32, 64);
    if (l < 32) {
        red2[w * 64 + lr]      = part[0];
        red2[w * 64 + 32 + lr] = part[1];
    }
    __syncthreads();
    if (tid < 64) {
        a2[(size_t)b * 1024 + s0 + tid] =
            red2[tid] + red2[64 + tid] + red2[128 + tid] + red2[192 + tid];
    }
}

// ---------------- K3: per-batch softmax (redundant per ct-block) + context ----------------
__global__ __launch_bounds__(256) void softmax_context(const float* __restrict__ x,
                                                       const float* __restrict__ a2,
                                                       float* __restrict__ a3,
                                                       float* __restrict__ ctx) {
    __shared__ float sm[1024];
    __shared__ float red[8];
    const int tid = threadIdx.x;
    const int b = blockIdx.y, ct = blockIdx.x;  // 32 ct x 16 rows
    const int wave = tid >> 6, lane = tid & 63;

    float4 v = ((const float4*)(a2 + (size_t)b * 1024))[tid];
    float m = fmaxf(fmaxf(v.x, v.y), fmaxf(v.z, v.w));
    #pragma unroll
    for (int off = 32; off >= 1; off >>= 1) m = fmaxf(m, __shfl_xor(m, off, 64));
    if (lane == 0) red[wave] = m;
    __syncthreads();
    m = fmaxf(fmaxf(red[0], red[1]), fmaxf(red[2], red[3]));
    float e0 = expf(v.x - m), e1 = expf(v.y - m), e2 = expf(v.z - m), e3 = expf(v.w - m);
    float s = e0 + e1 + e2 + e3;
    #pragma unroll
    for (int off = 32; off >= 1; off >>= 1) s += __shfl_xor(s, off, 64);
    if (lane == 0) red[4 + wave] = s;
    __syncthreads();
    s = red[4] + red[5] + red[6] + red[7];
    float inv = 1.f / s;
    float4 o = {e0 * inv, e1 * inv, e2 * inv, e3 * inv};
    ((float4*)sm)[tid] = o;
    if (ct == 0) ((float4*)(a3 + (size_t)b * 1024))[tid] = o;
    __syncthreads();

    const float* xb = x + ((size_t)b << 19);
    #pragma unroll
    for (int r = 0; r < 4; ++r) {
        int c = ct * 16 + wave * 4 + r;
        const float4* row = (const float4*)(xb + (size_t)c * 1024);
        float sum = 0.f;
        #pragma unroll
        for (int it = 0; it < 4; ++it) {
            int idx = it * 64 + lane;
            float4 xv = row[idx];
            float4 av = *(const float4*)&sm[idx * 4];
            sum = fmaf(xv.x, av.x, fmaf(xv.y, av.y, fmaf(xv.z, av.z, fmaf(xv.w, av.w, sum))));
        }
        #pragma unroll
        for (int off = 32; off >= 1; off >>= 1) sum += __shfl_xor(sum, off, 64);
        if (lane == 0) ctx[(size_t)b * 512 + c] = sum;
    }
}

extern "C" void kernel_launch(void* const* d_in, const int* in_sizes, int n_in,
                              void* d_out, int out_size, void* d_ws, size_t ws_size,
                              hipStream_t stream) {
    const float* x     = (const float*)d_in[0];
    const float* h     = (const float*)d_in[1];
    const float* Wc    = (const float*)d_in[2];
    const float* Wlin  = (const float*)d_in[3];
    const float* blin  = (const float*)d_in[4];
    const float* Wattn = (const float*)d_in[5];

    float* out = (float*)d_out;
    float* a3  = out;               // 32*1024
    float* ctx = out + 32 * 1024;   // 32*512

    char* ws = (char*)d_ws;
    float* h3 = (float*)ws;                            // 32 KB
    float* a2 = (float*)(ws + 32768);                  // 128 KB
    bf16* Whi = (bf16*)(ws + 32768 + 131072);          // 256 KB
    bf16* Wlo = (bf16*)(ws + 32768 + 131072 + 262144); // 256 KB (total 672 KB)

    hipLaunchKernelGGL(prep_kernel, dim3(96), dim3(256), 0, stream, h, Wlin, blin, Wc, h3, Whi, Wlo);
    hipLaunchKernelGGL(fused_mfma, dim3(512), dim3(256), 0, stream, x, Whi, Wlo, h3, Wattn, a2);
    hipLaunchKernelGGL(softmax_context, dim3(32, 32), dim3(256), 0, stream, x, a2, a3, ctx);
}

// Round 11
// 154.093 us; speedup vs baseline: 1.0239x; 1.0239x over previous
//
#include <hip/hip_runtime.h>
#include <hip/hip_bf16.h>
#include <cmath>

// AddictiveAttention: B=32, C=512, HW=1024, HID=256, MEM=256
// out = [a3: 32*1024 | context: 32*512] f32
//
// K1 prep: h3 = h@Wlin.T + blin ; W_conv1 -> Whi/Wlo bf16 split
// K2 fused_mfma (v4): 32x32x16 MFMA; ONE barrier per K-tile; per-wave-private
//    B-frag build from LDS xbuf (global_load_lds dbuf, issue-early); A=W from
//    global (L1/L2-hot); 3-term split product; tanh+Wattn k-reduce -> a2
// K3 softmax_context: softmax(a2[b]) -> a3, context

typedef __bf16 bf16;
typedef __attribute__((ext_vector_type(8))) __bf16 bf16x8;
typedef __attribute__((ext_vector_type(16))) float f32x16;

// ---------------- K1: prep (h3 + W split) ----------------
__global__ __launch_bounds__(256) void prep_kernel(const float* __restrict__ h,
                                                   const float* __restrict__ Wlin,
                                                   const float* __restrict__ blin,
                                                   const float* __restrict__ Wc,
                                                   float* __restrict__ h3,
                                                   bf16* __restrict__ Whi,
                                                   bf16* __restrict__ Wlo) {
    const int tid = threadIdx.x;
    if (blockIdx.x < 32) {
        const int b = blockIdx.x;
        __shared__ float hs[256];
        hs[tid] = h[b * 256 + tid];
        __syncthreads();
        const float4* wr = (const float4*)(Wlin + (size_t)tid * 256);
        float acc = blin[tid];
        #pragma unroll 8
        for (int q = 0; q < 64; ++q) {
            float4 w = wr[q];
            float4 hv = *(const float4*)&hs[q * 4];
            acc = fmaf(w.x, hv.x, fmaf(w.y, hv.y, fmaf(w.z, hv.z, fmaf(w.w, hv.w, acc))));
        }
        h3[b * 256 + tid] = acc;
    } else {
        const int e0 = (blockIdx.x - 32) * 2048 + tid * 8;
        float4 v0 = *(const float4*)(Wc + e0);
        float4 v1 = *(const float4*)(Wc + e0 + 4);
        float vs[8] = {v0.x, v0.y, v0.z, v0.w, v1.x, v1.y, v1.z, v1.w};
        bf16x8 vh, vl;
        #pragma unroll
        for (int j = 0; j < 8; ++j) {
            bf16 hi = (bf16)vs[j];
            float r = vs[j] - (float)hi;
            vh[j] = hi;
            vl[j] = (bf16)r;
        }
        *(bf16x8*)&Whi[e0] = vh;
        *(bf16x8*)&Wlo[e0] = vl;
    }
}

// ---------------- K2: v4 fused MFMA ----------------
// Block: batch b x 64 s-cols, ALL 256 k. 4 waves; wave w: k in [64w, 64w+64),
// covering all 64 s (2mf x 2nf of 32x32x16). Per-wave-private frag builds.
__global__ __launch_bounds__(256, 3) void fused_mfma(const float* __restrict__ x,
                                                     const bf16* __restrict__ Whi,
                                                     const bf16* __restrict__ Wlo,
                                                     const float* __restrict__ h3,
                                                     const float* __restrict__ Wattn,
                                                     float* __restrict__ a2) {
    __shared__ float xbuf[2][64 * 64];   // 32 KB: x tile f32 [c][s], double-buffered
    __shared__ float red2[4 * 64];       // 1 KB

    const int tid = threadIdx.x;
    const int bid = blockIdx.x;
    // XCD-chunked swizzle (512 % 8 == 0 -> bijective): 4 whole batches per XCD
    const int wk = (bid & 7) * 64 + (bid >> 3);
    const int b  = wk >> 4;
    const int s0 = (wk & 15) * 64;

    const int w  = tid >> 6;   // wave 0..3 -> k in [64w, 64w+64)
    const int l  = tid & 63;
    const int h  = l >> 5;     // k-group half
    const int lr = l & 31;     // row/col within 32

    const float* xb = x + ((size_t)b << 19) + s0;

    // A base pointers (lane-fixed row, 8h element base)
    const bf16* aphi[2];
    const bf16* aplo[2];
    #pragma unroll
    for (int mf = 0; mf < 2; ++mf) {
        const size_t kr = (size_t)(64 * w + 32 * mf + lr) * 512 + 8 * h;
        aphi[mf] = Whi + kr;
        aplo[mf] = Wlo + kr;
    }

    f32x16 acc[2][2];
    #pragma unroll
    for (int mf = 0; mf < 2; ++mf)
        #pragma unroll
        for (int nf = 0; nf < 2; ++nf)
            #pragma unroll
            for (int r = 0; r < 16; ++r) acc[mf][nf][r] = 0.f;

    // ---- stage tile tt into xbuf[nb] via global_load_lds (4 x 16B / thread) ----
    auto stage = [&](int tt, int nb) {
        #pragma unroll
        for (int q = 0; q < 4; ++q) {
            const float* g = xb + (size_t)(tt * 64 + 16 * q + 4 * w + (l >> 4)) * 1024
                                + 4 * (l & 15);
            __builtin_amdgcn_global_load_lds(
                (const __attribute__((address_space(1))) void*)g,
                (__attribute__((address_space(3))) void*)((char*)&xbuf[nb][0] + q * 4096 + w * 1024),
                16, 0, 0);
        }
    };

    stage(0, 0);

    #pragma unroll 1
    for (int t = 0; t < 8; ++t) {
        const int cur = t & 1;
        const int c0 = t * 64;
        __syncthreads();                   // drains stage(t); xbuf[cur] ready
        if (t < 7) stage(t + 1, cur ^ 1);  // issue-early: HBM latency hides under compute

        #pragma unroll
        for (int kk = 0; kk < 4; ++kk) {
            // A-frags (global, L1/L2-hot)
            bf16x8 ah0 = *(const bf16x8*)(aphi[0] + c0 + 16 * kk);
            bf16x8 al0 = *(const bf16x8*)(aplo[0] + c0 + 16 * kk);
            bf16x8 ah1 = *(const bf16x8*)(aphi[1] + c0 + 16 * kk);
            bf16x8 al1 = *(const bf16x8*)(aplo[1] + c0 + 16 * kk);
            // B-frags: private build from xbuf (stride-64 b32, 2 lanes/bank = free)
            bf16x8 bh[2], bl[2];
            #pragma unroll
            for (int nf = 0; nf < 2; ++nf) {
                const int base = (16 * kk + 8 * h) * 64 + 32 * nf + lr;
                float f[8];
                #pragma unroll
                for (int j = 0; j < 8; ++j) f[j] = xbuf[cur][base + j * 64];
                #pragma unroll
                for (int j = 0; j < 8; ++j) {
                    bf16 hh = (bf16)f[j];
                    bh[nf][j] = hh;
                    bl[nf][j] = (bf16)(f[j] - (float)hh);
                }
            }
            // 12 MFMA: 2mf x 2nf x 3 terms
            acc[0][0] = __builtin_amdgcn_mfma_f32_32x32x16_bf16(ah0, bh[0], acc[0][0], 0, 0, 0);
            acc[0][0] = __builtin_amdgcn_mfma_f32_32x32x16_bf16(ah0, bl[0], acc[0][0], 0, 0, 0);
            acc[0][0] = __builtin_amdgcn_mfma_f32_32x32x16_bf16(al0, bh[0], acc[0][0], 0, 0, 0);
            acc[0][1] = __builtin_amdgcn_mfma_f32_32x32x16_bf16(ah0, bh[1], acc[0][1], 0, 0, 0);
            acc[0][1] = __builtin_amdgcn_mfma_f32_32x32x16_bf16(ah0, bl[1], acc[0][1], 0, 0, 0);
            acc[0][1] = __builtin_amdgcn_mfma_f32_32x32x16_bf16(al0, bh[1], acc[0][1], 0, 0, 0);
            acc[1][0] = __builtin_amdgcn_mfma_f32_32x32x16_bf16(ah1, bh[0], acc[1][0], 0, 0, 0);
            acc[1][0] = __builtin_amdgcn_mfma_f32_32x32x16_bf16(ah1, bl[0], acc[1][0], 0, 0, 0);
            acc[1][0] = __builtin_amdgcn_mfma_f32_32x32x16_bf16(al1, bh[0], acc[1][0], 0, 0, 0);
            acc[1][1] = __builtin_amdgcn_mfma_f32_32x32x16_bf16(ah1, bh[1], acc[1][1], 0, 0, 0);
            acc[1][1] = __builtin_amdgcn_mfma_f32_32x32x16_bf16(ah1, bl[1], acc[1][1], 0, 0, 0);
            acc[1][1] = __builtin_amdgcn_mfma_f32_32x32x16_bf16(al1, bh[1], acc[1][1], 0, 0, 0);
        }
    }

    // ---- epilogue: tanh + Wattn k-reduce ----
    // C/D: col = lr (s rel 32nf), row = (reg&3) + 8*(reg>>2) + 4*h (+32mf +64w)
    const float* h3b = h3 + b * 256;
    float part[2] = {0.f, 0.f};
    #pragma unroll
    for (int mf = 0; mf < 2; ++mf) {
        #pragma unroll
        for (int r = 0; r < 16; ++r) {
            const int k = 64 * w + 32 * mf + (r & 3) + 8 * (r >> 2) + 4 * h;
            const float hv = h3b[k];
            const float wt = Wattn[k];
            part[0] += wt * tanhf(acc[mf][0][r] + hv);
            part[1] += wt * tanhf(acc[mf][1][r] + hv);
        }
    }
    part[0] += __shfl_xor(part[0], 32, 64);
    part[1] += __shfl_xor(part[1], 32, 64);
    if (l < 32) {
        red2[w * 64 + lr]      = part[0];
        red2[w * 64 + 32 + lr] = part[1];
    }
    __syncthreads();
    if (tid < 64) {
        a2[(size_t)b * 1024 + s0 + tid] =
            red2[tid] + red2[64 + tid] + red2[128 + tid] + red2[192 + tid];
    }
}

// ---------------- K3: per-batch softmax (redundant per ct-block) + context ----------------
__global__ __launch_bounds__(256) void softmax_context(const float* __restrict__ x,
                                                       const float* __restrict__ a2,
                                                       float* __restrict__ a3,
                                                       float* __restrict__ ctx) {
    __shared__ float sm[1024];
    __shared__ float red[8];
    const int tid = threadIdx.x;
    const int b = blockIdx.y, ct = blockIdx.x;  // 32 ct x 16 rows
    const int wave = tid >> 6, lane = tid & 63;

    float4 v = ((const float4*)(a2 + (size_t)b * 1024))[tid];
    float m = fmaxf(fmaxf(v.x, v.y), fmaxf(v.z, v.w));
    #pragma unroll
    for (int off = 32; off >= 1; off >>= 1) m = fmaxf(m, __shfl_xor(m, off, 64));
    if (lane == 0) red[wave] = m;
    __syncthreads();
    m = fmaxf(fmaxf(red[0], red[1]), fmaxf(red[2], red[3]));
    float e0 = expf(v.x - m), e1 = expf(v.y - m), e2 = expf(v.z - m), e3 = expf(v.w - m);
    float s = e0 + e1 + e2 + e3;
    #pragma unroll
    for (int off = 32; off >= 1; off >>= 1) s += __shfl_xor(s, off, 64);
    if (lane == 0) red[4 + wave] = s;
    __syncthreads();
    s = red[4] + red[5] + red[6] + red[7];
    float inv = 1.f / s;
    float4 o = {e0 * inv, e1 * inv, e2 * inv, e3 * inv};
    ((float4*)sm)[tid] = o;
    if (ct == 0) ((float4*)(a3 + (size_t)b * 1024))[tid] = o;
    __syncthreads();

    const float* xb = x + ((size_t)b << 19);
    #pragma unroll
    for (int r = 0; r < 4; ++r) {
        int c = ct * 16 + wave * 4 + r;
        const float4* row = (const float4*)(xb + (size_t)c * 1024);
        float sum = 0.f;
        #pragma unroll
        for (int it = 0; it < 4; ++it) {
            int idx = it * 64 + lane;
            float4 xv = row[idx];
            float4 av = *(const float4*)&sm[idx * 4];
            sum = fmaf(xv.x, av.x, fmaf(xv.y, av.y, fmaf(xv.z, av.z, fmaf(xv.w, av.w, sum))));
        }
        #pragma unroll
        for (int off = 32; off >= 1; off >>= 1) sum += __shfl_xor(sum, off, 64);
        if (lane == 0) ctx[(size_t)b * 512 + c] = sum;
    }
}

extern "C" void kernel_launch(void* const* d_in, const int* in_sizes, int n_in,
                              void* d_out, int out_size, void* d_ws, size_t ws_size,
                              hipStream_t stream) {
    const float* x     = (const float*)d_in[0];
    const float* h     = (const float*)d_in[1];
    const float* Wc    = (const float*)d_in[2];
    const float* Wlin  = (const float*)d_in[3];
    const float* blin  = (const float*)d_in[4];
    const float* Wattn = (const float*)d_in[5];

    float* out = (float*)d_out;
    float* a3  = out;               // 32*1024
    float* ctx = out + 32 * 1024;   // 32*512

    char* ws = (char*)d_ws;
    float* h3 = (float*)ws;                            // 32 KB
    float* a2 = (float*)(ws + 32768);                  // 128 KB
    bf16* Whi = (bf16*)(ws + 32768 + 131072);          // 256 KB
    bf16* Wlo = (bf16*)(ws + 32768 + 131072 + 262144); // 256 KB (total 672 KB)

    hipLaunchKernelGGL(prep_kernel, dim3(96), dim3(256), 0, stream, h, Wlin, blin, Wc, h3, Whi, Wlo);
    hipLaunchKernelGGL(fused_mfma, dim3(512), dim3(256), 0, stream, x, Whi, Wlo, h3, Wattn, a2);
    hipLaunchKernelGGL(softmax_context, dim3(32, 32), dim3(256), 0, stream, x, a2, a3, ctx);
}

// Round 12
// 145.736 us; speedup vs baseline: 1.0826x; 1.0573x over previous
//
#include <hip/hip_runtime.h>
#include <hip/hip_bf16.h>
#include <cmath>

// AddictiveAttention: B=32, C=512, HW=1024, HID=256, MEM=256
// out = [a3: 32*1024 | context: 32*512] f32
//
// K1 prep: h3 = h@Wlin.T + blin ; W_conv1 -> PERMUTED Whi/Wlo bf16 split
//    (fragment-order: chunk e=(kb*32+cc)*64+l <-> W[32kb+(l&31)][16cc+8(l>>5)..+8])
// K2 fused_mfma (v5): 32x32x16 MFMA; A-frags = single coalesced 16B/lane loads
//    from permuted W (L2-hot); B=x via global_load_lds dbuf + private frag build;
//    3-term split product; tanh+Wattn k-reduce -> a2
// K3 softmax_context: softmax(a2[b]) -> a3, context

typedef __bf16 bf16;
typedef __attribute__((ext_vector_type(8))) __bf16 bf16x8;
typedef __attribute__((ext_vector_type(16))) float f32x16;

// ---------------- K1: prep (h3 + W perm-split) ----------------
__global__ __launch_bounds__(256) void prep_kernel(const float* __restrict__ h,
                                                   const float* __restrict__ Wlin,
                                                   const float* __restrict__ blin,
                                                   const float* __restrict__ Wc,
                                                   float* __restrict__ h3,
                                                   bf16* __restrict__ Whi,
                                                   bf16* __restrict__ Wlo) {
    const int tid = threadIdx.x;
    if (blockIdx.x < 32) {
        const int b = blockIdx.x;
        __shared__ float hs[256];
        hs[tid] = h[b * 256 + tid];
        __syncthreads();
        const float4* wr = (const float4*)(Wlin + (size_t)tid * 256);
        float acc = blin[tid];
        #pragma unroll 8
        for (int q = 0; q < 64; ++q) {
            float4 w = wr[q];
            float4 hv = *(const float4*)&hs[q * 4];
            acc = fmaf(w.x, hv.x, fmaf(w.y, hv.y, fmaf(w.z, hv.z, fmaf(w.w, hv.w, acc))));
        }
        h3[b * 256 + tid] = acc;
    } else {
        // W perm split: 64 blocks x 256 threads, one bf16x8 chunk each.
        // e = (kb*32 + cc)*64 + l  <->  W[32kb + (l&31)][16cc + 8*(l>>5) .. +8]
        const int e  = (blockIdx.x - 32) * 256 + tid;  // 0..16383
        const int l  = e & 63;
        const int cc = (e >> 6) & 31;
        const int kb = e >> 11;
        const int row = 32 * kb + (l & 31);
        const int col = 16 * cc + 8 * (l >> 5);
        const float* src = Wc + (size_t)row * 512 + col;
        float4 v0 = *(const float4*)src;
        float4 v1 = *(const float4*)(src + 4);
        float vs[8] = {v0.x, v0.y, v0.z, v0.w, v1.x, v1.y, v1.z, v1.w};
        bf16x8 vh, vl;
        #pragma unroll
        for (int j = 0; j < 8; ++j) {
            bf16 hi = (bf16)vs[j];
            float r = vs[j] - (float)hi;
            vh[j] = hi;
            vl[j] = (bf16)r;
        }
        *(bf16x8*)&Whi[e * 8] = vh;
        *(bf16x8*)&Wlo[e * 8] = vl;
    }
}

// ---------------- K2: v5 fused MFMA ----------------
// Block: batch b x 64 s-cols, ALL 256 k. 4 waves; wave w: k in [64w, 64w+64),
// 2mf x 2nf of 32x32x16. A-frags coalesced from permuted W; B private build.
__global__ __launch_bounds__(256, 3) void fused_mfma(const float* __restrict__ x,
                                                     const bf16* __restrict__ Whi,
                                                     const bf16* __restrict__ Wlo,
                                                     const float* __restrict__ h3,
                                                     const float* __restrict__ Wattn,
                                                     float* __restrict__ a2) {
    __shared__ float xbuf[2][64 * 64];   // 32 KB: x tile f32 [c][s], double-buffered
    __shared__ float red2[4 * 64];       // 1 KB

    const int tid = threadIdx.x;
    const int bid = blockIdx.x;
    // XCD-chunked swizzle (512 % 8 == 0 -> bijective): 4 whole batches per XCD
    const int wk = (bid & 7) * 64 + (bid >> 3);
    const int b  = wk >> 4;
    const int s0 = (wk & 15) * 64;

    const int w  = tid >> 6;   // wave 0..3 -> k in [64w, 64w+64)
    const int l  = tid & 63;
    const int h  = l >> 5;     // k-group half
    const int lr = l & 31;     // row/col within 32

    const float* xb = x + ((size_t)b << 19) + s0;

    // Permuted-W fragment pointers: chunk (kb, ci, l) at [(kb*32+ci)*64+l]*8.
    // kb = 2w+mf; ci = 4t+kk; per-iter offset = ci*512 elements.
    const bf16* aph0 = Whi + ((size_t)(2 * w) * 32 * 64 + l) * 8;       // mf=0 hi
    const bf16* apl0 = Wlo + ((size_t)(2 * w) * 32 * 64 + l) * 8;       // mf=0 lo
    const bf16* aph1 = Whi + ((size_t)(2 * w + 1) * 32 * 64 + l) * 8;   // mf=1 hi
    const bf16* apl1 = Wlo + ((size_t)(2 * w + 1) * 32 * 64 + l) * 8;   // mf=1 lo

    f32x16 acc[2][2];
    #pragma unroll
    for (int mf = 0; mf < 2; ++mf)
        #pragma unroll
        for (int nf = 0; nf < 2; ++nf)
            #pragma unroll
            for (int r = 0; r < 16; ++r) acc[mf][nf][r] = 0.f;

    // ---- stage tile tt into xbuf[nb] via global_load_lds (4 x 16B / thread) ----
    auto stage = [&](int tt, int nb) {
        #pragma unroll
        for (int q = 0; q < 4; ++q) {
            const float* g = xb + (size_t)(tt * 64 + 16 * q + 4 * w + (l >> 4)) * 1024
                                + 4 * (l & 15);
            __builtin_amdgcn_global_load_lds(
                (const __attribute__((address_space(1))) void*)g,
                (__attribute__((address_space(3))) void*)((char*)&xbuf[nb][0] + q * 4096 + w * 1024),
                16, 0, 0);
        }
    };

    stage(0, 0);

    #pragma unroll 1
    for (int t = 0; t < 8; ++t) {
        const int cur = t & 1;
        __syncthreads();                   // drains stage(t); xbuf[cur] ready
        if (t < 7) stage(t + 1, cur ^ 1);  // issue-early: HBM latency hides under compute

        #pragma unroll
        for (int kk = 0; kk < 4; ++kk) {
            const int ci = t * 4 + kk;     // c-chunk16 index
            // A-frags: ONE coalesced 16B/lane load each (1KB/wave burst, L2-hot)
            bf16x8 ah0 = *(const bf16x8*)(aph0 + (size_t)ci * 512);
            bf16x8 al0 = *(const bf16x8*)(apl0 + (size_t)ci * 512);
            bf16x8 ah1 = *(const bf16x8*)(aph1 + (size_t)ci * 512);
            bf16x8 al1 = *(const bf16x8*)(apl1 + (size_t)ci * 512);
            // B-frags: private build from xbuf (stride-64 b32, 2 lanes/bank = free)
            bf16x8 bh[2], bl[2];
            #pragma unroll
            for (int nf = 0; nf < 2; ++nf) {
                const int base = (16 * kk + 8 * h) * 64 + 32 * nf + lr;
                float f[8];
                #pragma unroll
                for (int j = 0; j < 8; ++j) f[j] = xbuf[cur][base + j * 64];
                #pragma unroll
                for (int j = 0; j < 8; ++j) {
                    bf16 hh = (bf16)f[j];
                    bh[nf][j] = hh;
                    bl[nf][j] = (bf16)(f[j] - (float)hh);
                }
            }
            // 12 MFMA: 2mf x 2nf x 3 terms
            acc[0][0] = __builtin_amdgcn_mfma_f32_32x32x16_bf16(ah0, bh[0], acc[0][0], 0, 0, 0);
            acc[0][0] = __builtin_amdgcn_mfma_f32_32x32x16_bf16(ah0, bl[0], acc[0][0], 0, 0, 0);
            acc[0][0] = __builtin_amdgcn_mfma_f32_32x32x16_bf16(al0, bh[0], acc[0][0], 0, 0, 0);
            acc[0][1] = __builtin_amdgcn_mfma_f32_32x32x16_bf16(ah0, bh[1], acc[0][1], 0, 0, 0);
            acc[0][1] = __builtin_amdgcn_mfma_f32_32x32x16_bf16(ah0, bl[1], acc[0][1], 0, 0, 0);
            acc[0][1] = __builtin_amdgcn_mfma_f32_32x32x16_bf16(al0, bh[1], acc[0][1], 0, 0, 0);
            acc[1][0] = __builtin_amdgcn_mfma_f32_32x32x16_bf16(ah1, bh[0], acc[1][0], 0, 0, 0);
            acc[1][0] = __builtin_amdgcn_mfma_f32_32x32x16_bf16(ah1, bl[0], acc[1][0], 0, 0, 0);
            acc[1][0] = __builtin_amdgcn_mfma_f32_32x32x16_bf16(al1, bh[0], acc[1][0], 0, 0, 0);
            acc[1][1] = __builtin_amdgcn_mfma_f32_32x32x16_bf16(ah1, bh[1], acc[1][1], 0, 0, 0);
            acc[1][1] = __builtin_amdgcn_mfma_f32_32x32x16_bf16(ah1, bl[1], acc[1][1], 0, 0, 0);
            acc[1][1] = __builtin_amdgcn_mfma_f32_32x32x16_bf16(al1, bh[1], acc[1][1], 0, 0, 0);
        }
    }

    // ---- epilogue: tanh + Wattn k-reduce ----
    // C/D: col = lr (s rel 32nf), row = (reg&3) + 8*(reg>>2) + 4*h (+32mf +64w)
    const float* h3b = h3 + b * 256;
    float part[2] = {0.f, 0.f};
    #pragma unroll
    for (int mf = 0; mf < 2; ++mf) {
        #pragma unroll
        for (int r = 0; r < 16; ++r) {
            const int k = 64 * w + 32 * mf + (r & 3) + 8 * (r >> 2) + 4 * h;
            const float hv = h3b[k];
            const float wt = Wattn[k];
            part[0] += wt * tanhf(acc[mf][0][r] + hv);
            part[1] += wt * tanhf(acc[mf][1][r] + hv);
        }
    }
    part[0] += __shfl_xor(part[0], 32, 64);
    part[1] += __shfl_xor(part[1], 32, 64);
    if (l < 32) {
        red2[w * 64 + lr]      = part[0];
        red2[w * 64 + 32 + lr] = part[1];
    }
    __syncthreads();
    if (tid < 64) {
        a2[(size_t)b * 1024 + s0 + tid] =
            red2[tid] + red2[64 + tid] + red2[128 + tid] + red2[192 + tid];
    }
}

// ---------------- K3: per-batch softmax (redundant per ct-block) + context ----------------
__global__ __launch_bounds__(256) void softmax_context(const float* __restrict__ x,
                                                       const float* __restrict__ a2,
                                                       float* __restrict__ a3,
                                                       float* __restrict__ ctx) {
    __shared__ float sm[1024];
    __shared__ float red[8];
    const int tid = threadIdx.x;
    const int b = blockIdx.y, ct = blockIdx.x;  // 32 ct x 16 rows
    const int wave = tid >> 6, lane = tid & 63;

    float4 v = ((const float4*)(a2 + (size_t)b * 1024))[tid];
    float m = fmaxf(fmaxf(v.x, v.y), fmaxf(v.z, v.w));
    #pragma unroll
    for (int off = 32; off >= 1; off >>= 1) m = fmaxf(m, __shfl_xor(m, off, 64));
    if (lane == 0) red[wave] = m;
    __syncthreads();
    m = fmaxf(fmaxf(red[0], red[1]), fmaxf(red[2], red[3]));
    float e0 = expf(v.x - m), e1 = expf(v.y - m), e2 = expf(v.z - m), e3 = expf(v.w - m);
    float s = e0 + e1 + e2 + e3;
    #pragma unroll
    for (int off = 32; off >= 1; off >>= 1) s += __shfl_xor(s, off, 64);
    if (lane == 0) red[4 + wave] = s;
    __syncthreads();
    s = red[4] + red[5] + red[6] + red[7];
    float inv = 1.f / s;
    float4 o = {e0 * inv, e1 * inv, e2 * inv, e3 * inv};
    ((float4*)sm)[tid] = o;
    if (ct == 0) ((float4*)(a3 + (size_t)b * 1024))[tid] = o;
    __syncthreads();

    const float* xb = x + ((size_t)b << 19);
    #pragma unroll
    for (int r = 0; r < 4; ++r) {
        int c = ct * 16 + wave * 4 + r;
        const float4* row = (const float4*)(xb + (size_t)c * 1024);
        float sum = 0.f;
        #pragma unroll
        for (int it = 0; it < 4; ++it) {
            int idx = it * 64 + lane;
            float4 xv = row[idx];
            float4 av = *(const float4*)&sm[idx * 4];
            sum = fmaf(xv.x, av.x, fmaf(xv.y, av.y, fmaf(xv.z, av.z, fmaf(xv.w, av.w, sum))));
        }
        #pragma unroll
        for (int off = 32; off >= 1; off >>= 1) sum += __shfl_xor(sum, off, 64);
        if (lane == 0) ctx[(size_t)b * 512 + c] = sum;
    }
}

extern "C" void kernel_launch(void* const* d_in, const int* in_sizes, int n_in,
                              void* d_out, int out_size, void* d_ws, size_t ws_size,
                              hipStream_t stream) {
    const float* x     = (const float*)d_in[0];
    const float* h     = (const float*)d_in[1];
    const float* Wc    = (const float*)d_in[2];
    const float* Wlin  = (const float*)d_in[3];
    const float* blin  = (const float*)d_in[4];
    const float* Wattn = (const float*)d_in[5];

    float* out = (float*)d_out;
    float* a3  = out;               // 32*1024
    float* ctx = out + 32 * 1024;   // 32*512

    char* ws = (char*)d_ws;
    float* h3 = (float*)ws;                            // 32 KB
    float* a2 = (float*)(ws + 32768);                  // 128 KB
    bf16* Whi = (bf16*)(ws + 32768 + 131072);          // 256 KB (permuted)
    bf16* Wlo = (bf16*)(ws + 32768 + 131072 + 262144); // 256 KB (permuted)

    hipLaunchKernelGGL(prep_kernel, dim3(96), dim3(256), 0, stream, h, Wlin, blin, Wc, h3, Whi, Wlo);
    hipLaunchKernelGGL(fused_mfma, dim3(512), dim3(256), 0, stream, x, Whi, Wlo, h3, Wattn, a2);
    hipLaunchKernelGGL(softmax_context, dim3(32, 32), dim3(256), 0, stream, x, a2, a3, ctx);
}